// Round 3
// baseline (456.600 us; speedup 1.0000x reference)
//
#include <hip/hip_runtime.h>
#include <hip/hip_bf16.h>

// Problem constants (fixed by reference setup_inputs).
#define T_TOTAL 2048
#define BATCH   128
#define NIN     256
#define NOUT    128

// Decomposition: T-chunks x B-chunks. Warm-up recomputes trace history.
#define TC      256                 // timesteps per block
#define BC      4                   // batches per block
#define WARM    32                  // warm-up steps (0.5^32 ~ 2e-10 truncation)
#define NTC     (T_TOTAL / TC)      // 8
#define NBC     (BATCH / BC)        // 32
#define NBLOCKS (NTC * NBC)         // 256  (1 block/CU)
#define SUP     16                  // t-steps per supergroup -> K=64 per barrier
#define NSUP    (TC / SUP)          // 16 barriers per block (was 64)

#define OUT_ELEMS (NOUT * NIN)      // 32768

typedef __attribute__((ext_vector_type(8)))  __bf16 bf16x8;
typedef __attribute__((ext_vector_type(2)))  __bf16 bf16x2;
typedef __attribute__((ext_vector_type(16))) float  f32x16;
typedef __attribute__((ext_vector_type(4)))  unsigned uint32x4;

// packed f32x2 -> bf16x2 (v_cvt_pk_bf16_f32 on gfx950, RTNE)
static __device__ __forceinline__ unsigned pack_bf16(float a, float b) {
    bf16x2 v = { (__bf16)a, (__bf16)b };
    union { bf16x2 v; unsigned u; } c; c.v = v; return c.u;
}

// Fused STDP: fp32 trace scan in registers + bf16 MFMA.
// K-mapping within a supergroup: kk = s16*16 + bpair*8 + q*2 + delta
//   (s16 = 16-k MFMA sub-block, bpair = batch pair = khalf, q = t within quad,
//    delta = batch within pair). Each thread's 4 words per s16 are contiguous
//   -> ds_write_b128. LDS rows are 128 B (64 bf16 k's), XOR-swizzled in 16-B
//   chunks (phys_chunk = logical_chunk ^ (row&7)) -> minimum-cycle b128 R/W.
__global__ __launch_bounds__(512, 2)
void stdp_main(const float* __restrict__ in, const float* __restrict__ outs,
               float* __restrict__ dst, int nslots, int use_atomic)
{
    __shared__ __align__(16) unsigned tr_lds[2][NIN * 32];   // 64 KB, B operand (trace, n=i)
    __shared__ __align__(16) unsigned ot_lds[2][NOUT * 32];  // 32 KB, A operand (spikes, m=o)

    const int tid = threadIdx.x;
    const int bc  = blockIdx.x % NBC;
    const int tc  = blockIdx.x / NBC;
    const int b0  = bc * BC;
    const int t0  = tc * TC;

    // B role: thread -> (i = tid&255, batch pair bh), scans 2 chains
    const int i_idx = tid & 255;
    const int bh    = tid >> 8;          // 0/1
    // A role: thread -> (o = tid&127, batch pair bp, t-half th)
    const int o_idx = tid & 127;
    const int bp    = (tid >> 7) & 1;
    const int th    = (tid >> 8) & 1;

    float tr0 = 0.f, tr1 = 0.f;

    // ---- warm-up: trace scan only ----
    if (tc > 0) {
        for (int t = t0 - WARM; t < t0; t += 8) {
            float v0[8], v1[8];
#pragma unroll
            for (int u = 0; u < 8; ++u) {
                const size_t base = ((size_t)(t + u) * BATCH + b0 + 2 * bh) * NIN + i_idx;
                v0[u] = in[base];
                v1[u] = in[base + NIN];
            }
#pragma unroll
            for (int u = 0; u < 8; ++u) {
                tr0 = 0.5f * tr0 + v0[u];
                tr1 = 0.5f * tr1 + v1[u];
            }
        }
    }

    f32x16 acc[4];
#pragma unroll
    for (int j = 0; j < 4; ++j) acc[j] = (f32x16)(0.f);

    const int lane  = tid & 63;
    const int wv    = tid >> 6;          // 8 waves
    const int mt    = wv & 3;            // m-tile (out rows mt*32..+31)
    const int ntb   = (wv >> 2) * 4;     // n-tile base (4 tiles per wave)
    const int l31   = lane & 31;
    const int khalf = lane >> 5;         // selects batch pair in k
    const int sw    = l31 & 7;           // row bits for read-side swizzle

    for (int sg = 0; sg < NSUP; ++sg) {
        const int ts  = t0 + sg * SUP;
        const int buf = sg & 1;

        // ---- issue the full supergroup's loads up front (~98 KB/CU in flight) ----
        float vin0[SUP], vin1[SUP];
#pragma unroll
        for (int s = 0; s < SUP; ++s) {
            const size_t base = ((size_t)(ts + s) * BATCH + b0 + 2 * bh) * NIN + i_idx;
            vin0[s] = in[base];
            vin1[s] = in[base + NIN];
        }
        float vo0[8], vo1[8];
#pragma unroll
        for (int u = 0; u < 8; ++u) {
            const size_t baseO = ((size_t)(ts + th * 8 + u) * BATCH + b0 + 2 * bp) * NOUT + o_idx;
            vo0[u] = outs[baseO];
            vo1[u] = outs[baseO + NOUT];
        }

        // ---- scan (exact fp32) + stage B: one b128 write per s16 ----
#pragma unroll
        for (int s16 = 0; s16 < 4; ++s16) {
            unsigned bw[4];
#pragma unroll
            for (int q = 0; q < 4; ++q) {
                const int s = s16 * 4 + q;
                tr0 = 0.5f * tr0 + vin0[s];
                tr1 = 0.5f * tr1 + vin1[s];
                bw[q] = pack_bf16(tr0, tr1);
            }
            const int p = (s16 * 2 + bh) ^ (i_idx & 7);
            *(uint32x4*)&tr_lds[buf][i_idx * 32 + p * 4] = (uint32x4){bw[0], bw[1], bw[2], bw[3]};
        }

        // ---- stage A: two b128 writes (thread covers s16 = 2*th, 2*th+1) ----
#pragma unroll
        for (int e = 0; e < 2; ++e) {
            const int s16 = th * 2 + e;
            unsigned aw[4];
#pragma unroll
            for (int q = 0; q < 4; ++q) {
                const int u = e * 4 + q;
                aw[q] = pack_bf16(vo0[u], vo1[u]);
            }
            const int p = (s16 * 2 + bp) ^ (o_idx & 7);
            *(uint32x4*)&ot_lds[buf][o_idx * 32 + p * 4] = (uint32x4){aw[0], aw[1], aw[2], aw[3]};
        }

        __syncthreads();   // one barrier per supergroup (double-buffered LDS)

        // ---- 16 MFMAs per wave: 4 sub-k blocks x 4 n-tiles ----
#pragma unroll
        for (int s16 = 0; s16 < 4; ++s16) {
            const int pc = (s16 * 2 + khalf) ^ sw;
            const bf16x8 a = *(const bf16x8*)&ot_lds[buf][(mt * 32 + l31) * 32 + pc * 4];
#pragma unroll
            for (int j = 0; j < 4; ++j) {
                const int row = (ntb + j) * 32 + l31;
                const bf16x8 b = *(const bf16x8*)&tr_lds[buf][row * 32 + pc * 4];
                acc[j] = __builtin_amdgcn_mfma_f32_32x32x16_bf16(a, b, acc[j], 0, 0, 0);
            }
        }
    }

    // ---- epilogue: D[row, col] -> dw[o = mt*32+row, i = ntile*32+col] ----
    float* base = dst + (size_t)(use_atomic ? (blockIdx.x % nslots) : blockIdx.x) * OUT_ELEMS;
#pragma unroll
    for (int j = 0; j < 4; ++j) {
        const int icol = (ntb + j) * 32 + l31;
#pragma unroll
        for (int r = 0; r < 16; ++r) {
            const int row = (r & 3) + 8 * (r >> 2) + 4 * khalf;
            const int o   = mt * 32 + row;
            const float v = acc[j][r];
            if (use_atomic) atomicAdd(&base[o * NIN + icol], v);
            else            base[o * NIN + icol] = v;
        }
    }
}

__global__ void zero_kernel(float* p, int n) {
    int i = blockIdx.x * blockDim.x + threadIdx.x;
    if (i < n) p[i] = 0.f;
}

__global__ __launch_bounds__(256)
void reduce_kernel(const float* __restrict__ ws, float* __restrict__ outp, int nslots) {
    const int idx = blockIdx.x * 256 + threadIdx.x;
    float s = 0.f;
    int k = 0;
    for (; k + 16 <= nslots; k += 16) {
        float v[16];
#pragma unroll
        for (int u = 0; u < 16; ++u) v[u] = ws[(size_t)(k + u) * OUT_ELEMS + idx];
#pragma unroll
        for (int u = 0; u < 16; ++u) s += v[u];
    }
    for (; k < nslots; ++k) s += ws[(size_t)k * OUT_ELEMS + idx];
    outp[idx] = s;
}

extern "C" void kernel_launch(void* const* d_in, const int* in_sizes, int n_in,
                              void* d_out, int out_size, void* d_ws, size_t ws_size,
                              hipStream_t stream) {
    const float* in   = (const float*)d_in[0];
    const float* outs = (const float*)d_in[1];
    float* out = (float*)d_out;
    float* ws  = (float*)d_ws;

    const size_t slot_bytes = (size_t)OUT_ELEMS * sizeof(float);

    if (ws_size >= (size_t)NBLOCKS * slot_bytes) {
        // plain per-block partials + reduce (preferred)
        stdp_main<<<NBLOCKS, 512, 0, stream>>>(in, outs, ws, NBLOCKS, 0);
        reduce_kernel<<<OUT_ELEMS / 256, 256, 0, stream>>>(ws, out, NBLOCKS);
    } else if (ws_size >= 16 * slot_bytes) {
        // 16 shared slots, atomic accumulation
        zero_kernel<<<(16 * OUT_ELEMS + 255) / 256, 256, 0, stream>>>(ws, 16 * OUT_ELEMS);
        stdp_main<<<NBLOCKS, 512, 0, stream>>>(in, outs, ws, 16, 1);
        reduce_kernel<<<OUT_ELEMS / 256, 256, 0, stream>>>(ws, out, 16);
    } else {
        // last resort: atomics straight into d_out
        zero_kernel<<<(OUT_ELEMS + 255) / 256, 256, 0, stream>>>(out, OUT_ELEMS);
        stdp_main<<<NBLOCKS, 512, 0, stream>>>(in, outs, out, 1, 1);
    }
}